// Round 1
// baseline (1380.518 us; speedup 1.0000x reference)
//
#include <hip/hip_runtime.h>
#include <math.h>

// ---------------------------------------------------------------------------
// Problem constants
//   B=2048 images, H=W=16, DICT=14, SE=8, CE=16, ESZ=512, NZ=512
//   output: (2048, 2048) f32
// ---------------------------------------------------------------------------

// ---------------------------------------------------------------------------
// K0: normalized embedding table: table = se / max(||row||, 1)
// ---------------------------------------------------------------------------
__global__ __launch_bounds__(128) void prep_table_kernel(
    const float* __restrict__ se, float* __restrict__ tbl)
{
  int t = threadIdx.x;
  if (t < 112) {
    int r = t >> 3;
    float ss = 0.f;
    #pragma unroll
    for (int i = 0; i < 8; ++i) { float v = se[r * 8 + i]; ss += v * v; }
    float n = fmaxf(sqrtf(ss), 1.0f);
    tbl[t] = se[t] / n;
  }
}

// ---------------------------------------------------------------------------
// K1: per-row normalize of a (rows x 512) matrix: out = in / (sqrt(sum^2)+eps)
// one block per row, 256 threads, 2 elems/thread
// ---------------------------------------------------------------------------
__global__ __launch_bounds__(256) void norm_rows_kernel(
    const float* __restrict__ in, float* __restrict__ out, float eps)
{
  int row = blockIdx.x, t = threadIdx.x;
  float2 v = *reinterpret_cast<const float2*>(in + (size_t)row * 512 + t * 2);
  float ss = v.x * v.x + v.y * v.y;
  #pragma unroll
  for (int m = 32; m >= 1; m >>= 1) ss += __shfl_xor(ss, m, 64);
  __shared__ float wsum[4];
  int lane = t & 63, wid = t >> 6;
  if (lane == 0) wsum[wid] = ss;
  __syncthreads();
  float tot = wsum[0] + wsum[1] + wsum[2] + wsum[3];
  float inv = 1.0f / (sqrtf(tot) + eps);
  float2 o; o.x = v.x * inv; o.y = v.y * inv;
  *reinterpret_cast<float2*>(out + (size_t)row * 512 + t * 2) = o;
}

// ---------------------------------------------------------------------------
// K2: fused tower: gather+embed-conv(8->16) -> conv1(16->16,relu)
//     -> conv2(16->32,relu) -> act[b][oc*256 + y*16 + x]
// delta_mode=0: x = table[s], conv_embed + bias
// delta_mode=1: x = table[s'] - table[s], conv_embed without bias (biases cancel)
// one block per image, 256 threads = 16x16 spatial
// ---------------------------------------------------------------------------
__global__ __launch_bounds__(256) void tower_kernel(
    const int* __restrict__ s, const int* __restrict__ sp,
    const float* __restrict__ table,
    const float* __restrict__ ew, const float* __restrict__ eb,
    const float* __restrict__ c1w, const float* __restrict__ c1b,
    const float* __restrict__ c2w, const float* __restrict__ c2b,
    float* __restrict__ act, int delta_mode)
{
  __shared__ float tbl[14][8];
  __shared__ float bufA[8][18][18];    // gathered input, zero halo
  __shared__ float bufB[16][18][18];   // embed-conv out, zero halo
  __shared__ float bufC[16][18][18];   // conv1 out, zero halo

  int b = blockIdx.x, tid = threadIdx.x;
  int y = tid >> 4, x = tid & 15;

  if (tid < 112) ((float*)tbl)[tid] = table[tid];
  {
    float* za = (float*)bufA;
    for (int i = tid; i < 8 * 324; i += 256) za[i] = 0.f;
    float* zb = (float*)bufB;
    for (int i = tid; i < 16 * 324; i += 256) zb[i] = 0.f;
    float* zc = (float*)bufC;
    for (int i = tid; i < 16 * 324; i += 256) zc[i] = 0.f;
  }
  __syncthreads();

  // gather
  {
    int sv = s[(size_t)b * 256 + tid];
    if (delta_mode) {
      int spv = sp[(size_t)b * 256 + tid];
      #pragma unroll
      for (int c = 0; c < 8; ++c)
        bufA[c][y + 1][x + 1] = tbl[spv][c] - tbl[sv][c];
    } else {
      #pragma unroll
      for (int c = 0; c < 8; ++c)
        bufA[c][y + 1][x + 1] = tbl[sv][c];
    }
  }
  __syncthreads();

  // embed conv 8 -> 16 (no activation)
  {
    float p[72];
    #pragma unroll
    for (int c = 0; c < 8; ++c)
      #pragma unroll
      for (int ky = 0; ky < 3; ++ky)
        #pragma unroll
        for (int kx = 0; kx < 3; ++kx)
          p[c * 9 + ky * 3 + kx] = bufA[c][y + ky][x + kx];
    #pragma unroll
    for (int oc = 0; oc < 16; ++oc) {
      float acc = delta_mode ? 0.f : eb[oc];
      const float* wp = ew + oc * 72;
      #pragma unroll
      for (int i = 0; i < 72; ++i) acc = fmaf(p[i], wp[i], acc);
      bufB[oc][y + 1][x + 1] = acc;
    }
  }
  __syncthreads();

  // conv1 16 -> 16, relu
  {
    float acc[16];
    #pragma unroll
    for (int oc = 0; oc < 16; ++oc) acc[oc] = c1b[oc];
    for (int ic = 0; ic < 16; ++ic) {
      float p[9];
      #pragma unroll
      for (int ky = 0; ky < 3; ++ky)
        #pragma unroll
        for (int kx = 0; kx < 3; ++kx)
          p[ky * 3 + kx] = bufB[ic][y + ky][x + kx];
      #pragma unroll
      for (int oc = 0; oc < 16; ++oc) {
        const float* wp = c1w + (oc * 16 + ic) * 9;
        #pragma unroll
        for (int k = 0; k < 9; ++k) acc[oc] = fmaf(p[k], wp[k], acc[oc]);
      }
    }
    #pragma unroll
    for (int oc = 0; oc < 16; ++oc)
      bufC[oc][y + 1][x + 1] = fmaxf(acc[oc], 0.f);
  }
  __syncthreads();

  // conv2 16 -> 32, relu, store flattened NCHW
  {
    float acc[32];
    #pragma unroll
    for (int oc = 0; oc < 32; ++oc) acc[oc] = c2b[oc];
    for (int ic = 0; ic < 16; ++ic) {
      float p[9];
      #pragma unroll
      for (int ky = 0; ky < 3; ++ky)
        #pragma unroll
        for (int kx = 0; kx < 3; ++kx)
          p[ky * 3 + kx] = bufC[ic][y + ky][x + kx];
      #pragma unroll
      for (int oc = 0; oc < 32; ++oc) {
        const float* wp = c2w + (oc * 16 + ic) * 9;
        #pragma unroll
        for (int k = 0; k < 9; ++k) acc[oc] = fmaf(p[k], wp[k], acc[oc]);
      }
    }
    float* ap = act + (size_t)b * 8192 + tid;
    #pragma unroll
    for (int oc = 0; oc < 32; ++oc)
      ap[oc * 256] = fmaxf(acc[oc], 0.f);
  }
}

// ---------------------------------------------------------------------------
// K3: C[m][n] = scale * ( sum_k A[m][k]*B[row(n)][k] + bias[n] )
//     row(n) = gather ? gather[n] : n ; scale = scale_p ? exp(scale_p[0]) : 1
// BM=BN=64, BK=16, 256 threads, 4x4 microtile, register prefetch
// ---------------------------------------------------------------------------
__global__ __launch_bounds__(256) void gemm_bt_kernel(
    const float* __restrict__ A, const float* __restrict__ B,
    const float* __restrict__ bias, const int* __restrict__ gather,
    const float* __restrict__ scale_p, float* __restrict__ C,
    int M, int N, int K)
{
  __shared__ float As[16][64];
  __shared__ float Bs[16][64];

  int t = threadIdx.x;
  int m0 = blockIdx.x * 64, n0 = blockIdx.y * 64;
  int lm = t >> 2, lc = t & 3;           // staging: row within tile, k-quad
  const float* Ap = A + (size_t)(m0 + lm) * K + lc * 4;
  int nrow = n0 + lm;
  int brow = gather ? gather[nrow] : nrow;
  const float* Bp = B + (size_t)brow * K + lc * 4;

  float4 ra = *reinterpret_cast<const float4*>(Ap);
  float4 rb = *reinterpret_cast<const float4*>(Bp);

  int tm = t >> 4, tn = t & 15;          // compute: 16x16 thread grid
  float acc[4][4];
  #pragma unroll
  for (int i = 0; i < 4; ++i)
    #pragma unroll
    for (int j = 0; j < 4; ++j) acc[i][j] = 0.f;

  int nk = K >> 4;
  for (int kt = 0; kt < nk; ++kt) {
    As[lc * 4 + 0][lm] = ra.x; As[lc * 4 + 1][lm] = ra.y;
    As[lc * 4 + 2][lm] = ra.z; As[lc * 4 + 3][lm] = ra.w;
    Bs[lc * 4 + 0][lm] = rb.x; Bs[lc * 4 + 1][lm] = rb.y;
    Bs[lc * 4 + 2][lm] = rb.z; Bs[lc * 4 + 3][lm] = rb.w;
    __syncthreads();
    if (kt + 1 < nk) {
      ra = *reinterpret_cast<const float4*>(Ap + (kt + 1) * 16);
      rb = *reinterpret_cast<const float4*>(Bp + (kt + 1) * 16);
    }
    #pragma unroll
    for (int k = 0; k < 16; ++k) {
      float4 av = *reinterpret_cast<const float4*>(&As[k][tm * 4]);
      float4 bv = *reinterpret_cast<const float4*>(&Bs[k][tn * 4]);
      float a4[4] = {av.x, av.y, av.z, av.w};
      float b4[4] = {bv.x, bv.y, bv.z, bv.w};
      #pragma unroll
      for (int i = 0; i < 4; ++i)
        #pragma unroll
        for (int j = 0; j < 4; ++j)
          acc[i][j] = fmaf(a4[i], b4[j], acc[i][j]);
    }
    __syncthreads();
  }

  float scl = scale_p ? expf(scale_p[0]) : 1.0f;
  #pragma unroll
  for (int i = 0; i < 4; ++i) {
    int row = m0 + tm * 4 + i;
    #pragma unroll
    for (int j = 0; j < 4; ++j) {
      int col = n0 + tn * 4 + j;
      float v = acc[i][j];
      if (bias) v += bias[col];
      v *= scl;
      C[(size_t)row * N + col] = v;
    }
  }
}

// ---------------------------------------------------------------------------
// K4: per-row argmax over 512 scores (numpy first-occurrence tie-break)
// ---------------------------------------------------------------------------
__global__ __launch_bounds__(256) void argmax_rows_kernel(
    const float* __restrict__ S, int* __restrict__ inds)
{
  __shared__ float vals[256];
  __shared__ int idxs[256];
  int row = blockIdx.x, t = threadIdx.x;
  float best = -INFINITY; int bi = 1 << 30;
  #pragma unroll
  for (int r = 0; r < 2; ++r) {
    int j = t + r * 256;
    float v = S[(size_t)row * 512 + j];
    if (v > best) { best = v; bi = j; }   // strict > keeps earliest index
  }
  vals[t] = best; idxs[t] = bi;
  __syncthreads();
  for (int off = 128; off > 0; off >>= 1) {
    if (t < off) {
      float v2 = vals[t + off]; int i2 = idxs[t + off];
      if (v2 > vals[t] || (v2 == vals[t] && i2 < idxs[t])) {
        vals[t] = v2; idxs[t] = i2;
      }
    }
    __syncthreads();
  }
  if (t == 0) inds[row] = idxs[0];
}

// ---------------------------------------------------------------------------
// launch
// ---------------------------------------------------------------------------
extern "C" void kernel_launch(void* const* d_in, const int* in_sizes, int n_in,
                              void* d_out, int out_size, void* d_ws, size_t ws_size,
                              hipStream_t stream)
{
  const int*   s      = (const int*)  d_in[0];
  const int*   sprime = (const int*)  d_in[1];
  const float* se     = (const float*)d_in[2];
  const float* ew     = (const float*)d_in[3];
  const float* eb     = (const float*)d_in[4];
  const float* p1c1w  = (const float*)d_in[5];
  const float* p1c1b  = (const float*)d_in[6];
  const float* p1c2w  = (const float*)d_in[7];
  const float* p1c2b  = (const float*)d_in[8];
  const float* p1lw   = (const float*)d_in[9];
  const float* p1lb   = (const float*)d_in[10];
  const float* p2c1w  = (const float*)d_in[11];
  const float* p2c1b  = (const float*)d_in[12];
  const float* p2c2w  = (const float*)d_in[13];
  const float* p2c2b  = (const float*)d_in[14];
  const float* p2lw   = (const float*)d_in[15];
  const float* p2lb   = (const float*)d_in[16];
  const float* zv     = (const float*)d_in[17];
  const float* scale  = (const float*)d_in[18];
  float* out = (float*)d_out;

  // workspace layout (floats)
  float* w    = (float*)d_ws;
  float* tbl  = w;                      // 128
  float* zn   = tbl + 128;              // 512*512
  float* e1   = zn + 512 * 512;         // 2048*512
  float* e2   = e1 + 2048 * 512;        // 2048*512
  float* sc   = e2 + 2048 * 512;        // 2048*512
  int*   zi   = (int*)(sc + 2048 * 512);// 2048
  float* act  = (float*)(zi + 2048);    // 2048*8192

  prep_table_kernel<<<1, 128, 0, stream>>>(se, tbl);
  norm_rows_kernel<<<512, 256, 0, stream>>>(zv, zn, 0.0f);

  // tower 1 (s) -> act -> e1 (normalized)
  tower_kernel<<<2048, 256, 0, stream>>>(s, sprime, tbl, ew, eb,
                                         p1c1w, p1c1b, p1c2w, p1c2b, act, 0);
  gemm_bt_kernel<<<dim3(32, 8), 256, 0, stream>>>(act, p1lw, p1lb, nullptr,
                                                  nullptr, e1, 2048, 512, 8192);
  norm_rows_kernel<<<2048, 256, 0, stream>>>(e1, e1, 1e-4f);

  // tower 2 (delta) -> act -> e2 (normalized)
  tower_kernel<<<2048, 256, 0, stream>>>(s, sprime, tbl, ew, eb,
                                         p2c1w, p2c1b, p2c2w, p2c2b, act, 1);
  gemm_bt_kernel<<<dim3(32, 8), 256, 0, stream>>>(act, p2lw, p2lb, nullptr,
                                                  nullptr, e2, 2048, 512, 8192);
  norm_rows_kernel<<<2048, 256, 0, stream>>>(e2, e2, 1e-4f);

  // scores = e2 @ zn^T -> argmax -> gathered final GEMM into d_out
  gemm_bt_kernel<<<dim3(32, 8), 256, 0, stream>>>(e2, zn, nullptr, nullptr,
                                                  nullptr, sc, 2048, 512, 512);
  argmax_rows_kernel<<<2048, 256, 0, stream>>>(sc, zi);
  gemm_bt_kernel<<<dim3(32, 32), 256, 0, stream>>>(e1, zn, nullptr, zi,
                                                   scale, out, 2048, 2048, 512);
}

// Round 2
// 911.271 us; speedup vs baseline: 1.5149x; 1.5149x over previous
//
#include <hip/hip_runtime.h>
#include <math.h>

// ---------------------------------------------------------------------------
// Problem constants: B=2048, H=W=16, DICT=14, SE=8, CE=16, ESZ=512, NZ=512
// Output: (2048, 2048) f32
// ---------------------------------------------------------------------------

typedef __attribute__((ext_vector_type(8))) __bf16 bf16x8;
typedef __attribute__((ext_vector_type(4))) float f32x4;
typedef __attribute__((ext_vector_type(8))) unsigned short ushort8;
typedef __attribute__((ext_vector_type(4))) unsigned short ushort4v;
typedef __attribute__((ext_vector_type(2))) unsigned short ushort2v;

__device__ __forceinline__ unsigned short f2bf_trunc(float x) {
  union { float f; unsigned u; } v; v.f = x;
  return (unsigned short)(v.u >> 16);
}
__device__ __forceinline__ float bf2f(unsigned short h) {
  union { float f; unsigned u; } v; v.u = ((unsigned)h) << 16;
  return v.f;
}
__device__ __forceinline__ void gload_lds16(const void* g, void* l) {
  __builtin_amdgcn_global_load_lds(
      (const __attribute__((address_space(1))) unsigned int*)g,
      (__attribute__((address_space(3))) unsigned int*)l, 16, 0, 0);
}

// ---------------------------------------------------------------------------
// K0: normalized embedding table: table = se / max(||row||, 1)
// ---------------------------------------------------------------------------
__global__ __launch_bounds__(128) void prep_table_kernel(
    const float* __restrict__ se, float* __restrict__ tbl)
{
  int t = threadIdx.x;
  if (t < 112) {
    int r = t >> 3;
    float ss = 0.f;
    #pragma unroll
    for (int i = 0; i < 8; ++i) { float v = se[r * 8 + i]; ss += v * v; }
    float n = fmaxf(sqrtf(ss), 1.0f);
    tbl[t] = se[t] / n;
  }
}

// ---------------------------------------------------------------------------
// K1: per-row normalize of (rows x 512): outf = in/(sqrt(sum^2)+eps),
// plus bf16 2-way split of the normalized row (o0 hi, o1 lo).
// ---------------------------------------------------------------------------
__global__ __launch_bounds__(256) void norm_split_kernel(
    const float* __restrict__ in, float* __restrict__ outf,
    unsigned short* __restrict__ o0, unsigned short* __restrict__ o1, float eps)
{
  int row = blockIdx.x, t = threadIdx.x;
  size_t base = (size_t)row * 512 + t * 2;
  float2 v = *reinterpret_cast<const float2*>(in + base);
  float ss = v.x * v.x + v.y * v.y;
  #pragma unroll
  for (int m = 32; m >= 1; m >>= 1) ss += __shfl_xor(ss, m, 64);
  __shared__ float wsum[4];
  int lane = t & 63, wid = t >> 6;
  if (lane == 0) wsum[wid] = ss;
  __syncthreads();
  float tot = wsum[0] + wsum[1] + wsum[2] + wsum[3];
  float inv = 1.0f / (sqrtf(tot) + eps);
  float a = v.x * inv, b = v.y * inv;
  if (outf) { float2 o; o.x = a; o.y = b; *reinterpret_cast<float2*>(outf + base) = o; }
  if (o0) {
    unsigned short ha = f2bf_trunc(a), hb = f2bf_trunc(b);
    ushort2v h0 = {ha, hb};
    *reinterpret_cast<ushort2v*>(o0 + base) = h0;
    ushort2v h1 = {f2bf_trunc(a - bf2f(ha)), f2bf_trunc(b - bf2f(hb))};
    *reinterpret_cast<ushort2v*>(o1 + base) = h1;
  }
}

// ---------------------------------------------------------------------------
// K1b: reduce KSPLIT partial slabs + bias, then row-normalize; emit f32
// and/or bf16 splits (nullable outputs).
// ---------------------------------------------------------------------------
__global__ __launch_bounds__(256) void reduce_norm_kernel(
    const float* __restrict__ P, int nslab, size_t slab_stride,
    const float* __restrict__ bias, float eps,
    float* __restrict__ outf, unsigned short* __restrict__ o0,
    unsigned short* __restrict__ o1)
{
  int row = blockIdx.x, t = threadIdx.x;
  size_t base = (size_t)row * 512 + t * 2;
  float ax = 0.f, ay = 0.f;
  for (int s = 0; s < nslab; ++s) {
    float2 p = *reinterpret_cast<const float2*>(P + s * slab_stride + base);
    ax += p.x; ay += p.y;
  }
  ax += bias[t * 2]; ay += bias[t * 2 + 1];
  float ss = ax * ax + ay * ay;
  #pragma unroll
  for (int m = 32; m >= 1; m >>= 1) ss += __shfl_xor(ss, m, 64);
  __shared__ float wsum[4];
  int lane = t & 63, wid = t >> 6;
  if (lane == 0) wsum[wid] = ss;
  __syncthreads();
  float tot = wsum[0] + wsum[1] + wsum[2] + wsum[3];
  float inv = 1.0f / (sqrtf(tot) + eps);
  float a = ax * inv, b = ay * inv;
  if (outf) { float2 o; o.x = a; o.y = b; *reinterpret_cast<float2*>(outf + base) = o; }
  if (o0) {
    unsigned short ha = f2bf_trunc(a), hb = f2bf_trunc(b);
    ushort2v h0 = {ha, hb};
    *reinterpret_cast<ushort2v*>(o0 + base) = h0;
    ushort2v h1 = {f2bf_trunc(a - bf2f(ha)), f2bf_trunc(b - bf2f(hb))};
    *reinterpret_cast<ushort2v*>(o1 + base) = h1;
  }
}

// ---------------------------------------------------------------------------
// K1c: elementwise split of f32 matrix into 2 or 3 bf16 split matrices
// ---------------------------------------------------------------------------
template<int NSPLIT>
__global__ __launch_bounds__(256) void split_kernel(
    const float* __restrict__ in, unsigned short* __restrict__ s0,
    unsigned short* __restrict__ s1, unsigned short* __restrict__ s2, int n4)
{
  int i = blockIdx.x * 256 + threadIdx.x;
  if (i >= n4) return;
  f32x4 v = *reinterpret_cast<const f32x4*>(in + (size_t)i * 4);
  ushort4v a, b, c;
  #pragma unroll
  for (int j = 0; j < 4; ++j) {
    float x = v[j];
    unsigned short h0 = f2bf_trunc(x);
    float r1 = x - bf2f(h0);
    unsigned short h1 = f2bf_trunc(r1);
    a[j] = h0; b[j] = h1;
    if constexpr (NSPLIT == 3) c[j] = f2bf_trunc(r1 - bf2f(h1));
  }
  *reinterpret_cast<ushort4v*>(s0 + (size_t)i * 4) = a;
  *reinterpret_cast<ushort4v*>(s1 + (size_t)i * 4) = b;
  if constexpr (NSPLIT == 3) *reinterpret_cast<ushort4v*>(s2 + (size_t)i * 4) = c;
}

// ---------------------------------------------------------------------------
// K2: fused tower (unchanged, verified round 1): gather+embed-conv(8->16)
//     -> conv1(16->16,relu) -> conv2(16->32,relu) -> act f32
// ---------------------------------------------------------------------------
__global__ __launch_bounds__(256) void tower_kernel(
    const int* __restrict__ s, const int* __restrict__ sp,
    const float* __restrict__ table,
    const float* __restrict__ ew, const float* __restrict__ eb,
    const float* __restrict__ c1w, const float* __restrict__ c1b,
    const float* __restrict__ c2w, const float* __restrict__ c2b,
    float* __restrict__ act, int delta_mode)
{
  __shared__ float tbl[14][8];
  __shared__ float bufA[8][18][18];
  __shared__ float bufB[16][18][18];
  __shared__ float bufC[16][18][18];

  int b = blockIdx.x, tid = threadIdx.x;
  int y = tid >> 4, x = tid & 15;

  if (tid < 112) ((float*)tbl)[tid] = table[tid];
  {
    float* za = (float*)bufA;
    for (int i = tid; i < 8 * 324; i += 256) za[i] = 0.f;
    float* zb = (float*)bufB;
    for (int i = tid; i < 16 * 324; i += 256) zb[i] = 0.f;
    float* zc = (float*)bufC;
    for (int i = tid; i < 16 * 324; i += 256) zc[i] = 0.f;
  }
  __syncthreads();

  {
    int sv = s[(size_t)b * 256 + tid];
    if (delta_mode) {
      int spv = sp[(size_t)b * 256 + tid];
      #pragma unroll
      for (int c = 0; c < 8; ++c)
        bufA[c][y + 1][x + 1] = tbl[spv][c] - tbl[sv][c];
    } else {
      #pragma unroll
      for (int c = 0; c < 8; ++c)
        bufA[c][y + 1][x + 1] = tbl[sv][c];
    }
  }
  __syncthreads();

  {
    float p[72];
    #pragma unroll
    for (int c = 0; c < 8; ++c)
      #pragma unroll
      for (int ky = 0; ky < 3; ++ky)
        #pragma unroll
        for (int kx = 0; kx < 3; ++kx)
          p[c * 9 + ky * 3 + kx] = bufA[c][y + ky][x + kx];
    #pragma unroll
    for (int oc = 0; oc < 16; ++oc) {
      float acc = delta_mode ? 0.f : eb[oc];
      const float* wp = ew + oc * 72;
      #pragma unroll
      for (int i = 0; i < 72; ++i) acc = fmaf(p[i], wp[i], acc);
      bufB[oc][y + 1][x + 1] = acc;
    }
  }
  __syncthreads();

  {
    float acc[16];
    #pragma unroll
    for (int oc = 0; oc < 16; ++oc) acc[oc] = c1b[oc];
    for (int ic = 0; ic < 16; ++ic) {
      float p[9];
      #pragma unroll
      for (int ky = 0; ky < 3; ++ky)
        #pragma unroll
        for (int kx = 0; kx < 3; ++kx)
          p[ky * 3 + kx] = bufB[ic][y + ky][x + kx];
      #pragma unroll
      for (int oc = 0; oc < 16; ++oc) {
        const float* wp = c1w + (oc * 16 + ic) * 9;
        #pragma unroll
        for (int k = 0; k < 9; ++k) acc[oc] = fmaf(p[k], wp[k], acc[oc]);
      }
    }
    #pragma unroll
    for (int oc = 0; oc < 16; ++oc)
      bufC[oc][y + 1][x + 1] = fmaxf(acc[oc], 0.f);
  }
  __syncthreads();

  {
    float acc[32];
    #pragma unroll
    for (int oc = 0; oc < 32; ++oc) acc[oc] = c2b[oc];
    for (int ic = 0; ic < 16; ++ic) {
      float p[9];
      #pragma unroll
      for (int ky = 0; ky < 3; ++ky)
        #pragma unroll
        for (int kx = 0; kx < 3; ++kx)
          p[ky * 3 + kx] = bufC[ic][y + ky][x + kx];
      #pragma unroll
      for (int oc = 0; oc < 32; ++oc) {
        const float* wp = c2w + (oc * 16 + ic) * 9;
        #pragma unroll
        for (int k = 0; k < 9; ++k) acc[oc] = fmaf(p[k], wp[k], acc[oc]);
      }
    }
    float* ap = act + (size_t)b * 8192 + tid;
    #pragma unroll
    for (int oc = 0; oc < 32; ++oc)
      ap[oc * 256] = fmaxf(acc[oc], 0.f);
  }
}

// ---------------------------------------------------------------------------
// K3: split-bf16 MFMA GEMM, C = A @ B^T (A: MxK, B: NxK), 128x128 tile, BK=32
//   NSPLIT=2 -> 3 products (hi*hi + hi*lo + lo*hi)      ~3e-5 rel err
//   NSPLIT=3 -> 6 products (all i+j<=2)                 ~1e-7 rel err
//   AF32:   A is f32 in global, split on the fly (reg-staged, swizzled ds_write)
//   GATHER: B row = gather[n]
//   FINAL:  multiply by exp(scale_p[0]), write C; else write partial slab z
// LDS layout per tile: [128][32] ushort, XOR swizzle cb ^= ((row>>1)&3)<<4
// applied identically on store and read sides (involution).
// ---------------------------------------------------------------------------
template<int NSPLIT, bool AF32, bool GATHER, bool FINAL>
__global__ __launch_bounds__(256) void mfma_gemm_kernel(
    const float* __restrict__ Af32,
    const unsigned short* __restrict__ A0, const unsigned short* __restrict__ A1,
    const unsigned short* __restrict__ B0, const unsigned short* __restrict__ B1,
    const unsigned short* __restrict__ B2,
    const int* __restrict__ gather, const float* __restrict__ scale_p,
    float* __restrict__ C, int M, int N, int K, int Ksub)
{
  __shared__ unsigned short ldsA[NSPLIT][4096];   // [128][32] each
  __shared__ unsigned short ldsB[NSPLIT][4096];

  const int t = threadIdx.x;
  const int lane = t & 63, wv = t >> 6;
  const int m0 = blockIdx.x * 128, n0 = blockIdx.y * 128;
  const long kbase = (long)blockIdx.z * Ksub;
  const int NT = Ksub >> 5;

  // gload_lds chunk geometry: chunk = wv + 4*r; row = chunk*16 + (lane>>2);
  // 16B piece at byte col (lane&3)*16 (pre-swizzled global source).
  const int st_row = lane >> 2;
  const int st_cb = (lane & 3) * 16;
  int srow[2]; long bgrow[2];
  #pragma unroll
  for (int r = 0; r < 2; ++r) {
    int chunk = wv + 4 * r;
    int row = chunk * 16 + st_row;
    srow[r] = row;
    long g = n0 + row;
    if (GATHER) g = gather[n0 + row];
    bgrow[r] = g;
  }

  const int wr = wv >> 1, wc = wv & 1;
  const int fr = lane & 15, kc = lane >> 4;

  f32x4 acc[4][4];
  #pragma unroll
  for (int mi = 0; mi < 4; ++mi)
    #pragma unroll
    for (int ni = 0; ni < 4; ++ni) acc[mi][ni] = (f32x4)0.f;

  const unsigned short* Bsp[3] = {B0, B1, B2};
  const unsigned short* Asp[2] = {A0, A1};

  for (int kt = 0; kt < NT; ++kt) {
    long k0 = kbase + (long)kt * 32;

    // ---- B staging: NSPLIT tiles via global_load_lds (async) ----
    #pragma unroll
    for (int sp = 0; sp < NSPLIT; ++sp) {
      #pragma unroll
      for (int r = 0; r < 2; ++r) {
        int row = srow[r];
        int c = st_cb ^ (((row >> 1) & 3) << 4);
        const unsigned short* gp = Bsp[sp] + bgrow[r] * (long)K + k0 + (c >> 1);
        gload_lds16(gp, &ldsB[sp][(wv + 4 * r) * 512]);
      }
    }
    // ---- A staging ----
    if constexpr (AF32) {
      // thread: col-quad (t&7), rows (t>>3)+32i ; perfectly coalesced f32 loads
      #pragma unroll
      for (int i = 0; i < 4; ++i) {
        int row = (t >> 3) + 32 * i;
        f32x4 v = *reinterpret_cast<const f32x4*>(
            Af32 + (size_t)(m0 + row) * K + k0 + (t & 7) * 4);
        int cb = ((t & 7) * 8) ^ (((row >> 1) & 3) << 4);
        ushort4v w0, w1, w2;
        #pragma unroll
        for (int j = 0; j < 4; ++j) {
          float x = v[j];
          unsigned short h0 = f2bf_trunc(x);
          float r1 = x - bf2f(h0);
          unsigned short h1 = f2bf_trunc(r1);
          w0[j] = h0; w1[j] = h1;
          if constexpr (NSPLIT == 3) w2[j] = f2bf_trunc(r1 - bf2f(h1));
        }
        *reinterpret_cast<ushort4v*>(&ldsA[0][row * 32 + (cb >> 1)]) = w0;
        *reinterpret_cast<ushort4v*>(&ldsA[1][row * 32 + (cb >> 1)]) = w1;
        if constexpr (NSPLIT == 3)
          *reinterpret_cast<ushort4v*>(&ldsA[2][row * 32 + (cb >> 1)]) = w2;
      }
    } else {
      #pragma unroll
      for (int sp = 0; sp < 2; ++sp) {   // pre-split A always 2-way
        #pragma unroll
        for (int r = 0; r < 2; ++r) {
          int row = srow[r];
          int c = st_cb ^ (((row >> 1) & 3) << 4);
          const unsigned short* gp = Asp[sp] + (size_t)(m0 + row) * K + k0 + (c >> 1);
          gload_lds16(gp, &ldsA[sp][(wv + 4 * r) * 512]);
        }
      }
    }
    __syncthreads();   // drains vmcnt (gload_lds) + lgkmcnt (ds_write)

    // ---- fragments: row = quadrant + frag*16 + (lane&15), 16B at kc*16^swz ----
    bf16x8 af[NSPLIT][4], bf[NSPLIT][4];
    #pragma unroll
    for (int sp = 0; sp < NSPLIT; ++sp) {
      #pragma unroll
      for (int mi = 0; mi < 4; ++mi) {
        int row = wr * 64 + mi * 16 + fr;
        int cb = (kc * 16) ^ (((row >> 1) & 3) << 4);
        af[sp][mi] = __builtin_bit_cast(
            bf16x8, *reinterpret_cast<const ushort8*>(&ldsA[sp][row * 32 + (cb >> 1)]));
      }
      #pragma unroll
      for (int ni = 0; ni < 4; ++ni) {
        int row = wc * 64 + ni * 16 + fr;
        int cb = (kc * 16) ^ (((row >> 1) & 3) << 4);
        bf[sp][ni] = __builtin_bit_cast(
            bf16x8, *reinterpret_cast<const ushort8*>(&ldsB[sp][row * 32 + (cb >> 1)]));
      }
    }
    #pragma unroll
    for (int mi = 0; mi < 4; ++mi)
      #pragma unroll
      for (int ni = 0; ni < 4; ++ni) {
        f32x4 c = acc[mi][ni];
        c = __builtin_amdgcn_mfma_f32_16x16x32_bf16(af[0][mi], bf[0][ni], c, 0, 0, 0);
        c = __builtin_amdgcn_mfma_f32_16x16x32_bf16(af[0][mi], bf[1][ni], c, 0, 0, 0);
        c = __builtin_amdgcn_mfma_f32_16x16x32_bf16(af[1][mi], bf[0][ni], c, 0, 0, 0);
        if constexpr (NSPLIT == 3) {
          c = __builtin_amdgcn_mfma_f32_16x16x32_bf16(af[1][mi], bf[1][ni], c, 0, 0, 0);
          c = __builtin_amdgcn_mfma_f32_16x16x32_bf16(af[0][mi], bf[2][ni], c, 0, 0, 0);
          c = __builtin_amdgcn_mfma_f32_16x16x32_bf16(af[2][mi], bf[0][ni], c, 0, 0, 0);
        }
        acc[mi][ni] = c;
      }
    __syncthreads();
  }

  // ---- epilogue: C/D layout col=lane&15, row=(lane>>4)*4+q (m89/m91) ----
  float scl = 1.0f;
  if (FINAL) scl = expf(scale_p[0]);
  float* Cp = FINAL ? C : C + (size_t)blockIdx.z * M * N;
  #pragma unroll
  for (int mi = 0; mi < 4; ++mi)
    #pragma unroll
    for (int ni = 0; ni < 4; ++ni) {
      int col = n0 + wc * 64 + ni * 16 + (lane & 15);
      #pragma unroll
      for (int q = 0; q < 4; ++q) {
        int row = m0 + wr * 64 + mi * 16 + (lane >> 4) * 4 + q;
        Cp[(size_t)row * N + col] = acc[mi][ni][q] * scl;
      }
    }
}

// ---------------------------------------------------------------------------
// K4: f32 VALU GEMM (verified round 1) — kept for the argmax score matrix
// ---------------------------------------------------------------------------
__global__ __launch_bounds__(256) void gemm_bt_kernel(
    const float* __restrict__ A, const float* __restrict__ B,
    const float* __restrict__ bias, const int* __restrict__ gather,
    const float* __restrict__ scale_p, float* __restrict__ C,
    int M, int N, int K)
{
  __shared__ float As[16][64];
  __shared__ float Bs[16][64];

  int t = threadIdx.x;
  int m0 = blockIdx.x * 64, n0 = blockIdx.y * 64;
  int lm = t >> 2, lc = t & 3;
  const float* Ap = A + (size_t)(m0 + lm) * K + lc * 4;
  int nrow = n0 + lm;
  int brow = gather ? gather[nrow] : nrow;
  const float* Bp = B + (size_t)brow * K + lc * 4;

  float4 ra = *reinterpret_cast<const float4*>(Ap);
  float4 rb = *reinterpret_cast<const float4*>(Bp);

  int tm = t >> 4, tn = t & 15;
  float acc[4][4];
  #pragma unroll
  for (int i = 0; i < 4; ++i)
    #pragma unroll
    for (int j = 0; j < 4; ++j) acc[i][j] = 0.f;

  int nk = K >> 4;
  for (int kt = 0; kt < nk; ++kt) {
    As[lc * 4 + 0][lm] = ra.x; As[lc * 4 + 1][lm] = ra.y;
    As[lc * 4 + 2][lm] = ra.z; As[lc * 4 + 3][lm] = ra.w;
    Bs[lc * 4 + 0][lm] = rb.x; Bs[lc * 4 + 1][lm] = rb.y;
    Bs[lc * 4 + 2][lm] = rb.z; Bs[lc * 4 + 3][lm] = rb.w;
    __syncthreads();
    if (kt + 1 < nk) {
      ra = *reinterpret_cast<const float4*>(Ap + (kt + 1) * 16);
      rb = *reinterpret_cast<const float4*>(Bp + (kt + 1) * 16);
    }
    #pragma unroll
    for (int k = 0; k < 16; ++k) {
      float4 av = *reinterpret_cast<const float4*>(&As[k][tm * 4]);
      float4 bv = *reinterpret_cast<const float4*>(&Bs[k][tn * 4]);
      float a4[4] = {av.x, av.y, av.z, av.w};
      float b4[4] = {bv.x, bv.y, bv.z, bv.w};
      #pragma unroll
      for (int i = 0; i < 4; ++i)
        #pragma unroll
        for (int j = 0; j < 4; ++j)
          acc[i][j] = fmaf(a4[i], b4[j], acc[i][j]);
    }
    __syncthreads();
  }

  float scl = scale_p ? expf(scale_p[0]) : 1.0f;
  #pragma unroll
  for (int i = 0; i < 4; ++i) {
    int row = m0 + tm * 4 + i;
    #pragma unroll
    for (int j = 0; j < 4; ++j) {
      int col = n0 + tn * 4 + j;
      float v = acc[i][j];
      if (bias) v += bias[col];
      v *= scl;
      C[(size_t)row * N + col] = v;
    }
  }
}

// ---------------------------------------------------------------------------
// K5: per-row argmax over 512 scores (numpy first-occurrence tie-break)
// ---------------------------------------------------------------------------
__global__ __launch_bounds__(256) void argmax_rows_kernel(
    const float* __restrict__ S, int* __restrict__ inds)
{
  __shared__ float vals[256];
  __shared__ int idxs[256];
  int row = blockIdx.x, t = threadIdx.x;
  float best = -INFINITY; int bi = 1 << 30;
  #pragma unroll
  for (int r = 0; r < 2; ++r) {
    int j = t + r * 256;
    float v = S[(size_t)row * 512 + j];
    if (v > best) { best = v; bi = j; }
  }
  vals[t] = best; idxs[t] = bi;
  __syncthreads();
  for (int off = 128; off > 0; off >>= 1) {
    if (t < off) {
      float v2 = vals[t + off]; int i2 = idxs[t + off];
      if (v2 > vals[t] || (v2 == vals[t] && i2 < idxs[t])) {
        vals[t] = v2; idxs[t] = i2;
      }
    }
    __syncthreads();
  }
  if (t == 0) inds[row] = idxs[0];
}

// ---------------------------------------------------------------------------
// launch
// ---------------------------------------------------------------------------
extern "C" void kernel_launch(void* const* d_in, const int* in_sizes, int n_in,
                              void* d_out, int out_size, void* d_ws, size_t ws_size,
                              hipStream_t stream)
{
  const int*   s      = (const int*)  d_in[0];
  const int*   sprime = (const int*)  d_in[1];
  const float* se     = (const float*)d_in[2];
  const float* ew     = (const float*)d_in[3];
  const float* eb     = (const float*)d_in[4];
  const float* p1c1w  = (const float*)d_in[5];
  const float* p1c1b  = (const float*)d_in[6];
  const float* p1c2w  = (const float*)d_in[7];
  const float* p1c2b  = (const float*)d_in[8];
  const float* p1lw   = (const float*)d_in[9];
  const float* p1lb   = (const float*)d_in[10];
  const float* p2c1w  = (const float*)d_in[11];
  const float* p2c1b  = (const float*)d_in[12];
  const float* p2c2w  = (const float*)d_in[13];
  const float* p2c2b  = (const float*)d_in[14];
  const float* p2lw   = (const float*)d_in[15];
  const float* p2lb   = (const float*)d_in[16];
  const float* zv     = (const float*)d_in[17];
  const float* scale  = (const float*)d_in[18];
  float* out = (float*)d_out;

  // ---- workspace layout (bytes, 256B-aligned; peak ~118 MB) ----
  char* w = (char*)d_ws;
  size_t off = 0;
  auto alloc = [&](size_t bytes) -> char* {
    char* p = w + off;
    off += (bytes + 255) & ~(size_t)255;
    return p;
  };
  float*  tbl  = (float*)alloc(128 * 4);
  float*  znf  = (float*)alloc((size_t)512 * 512 * 4);
  unsigned short* zn0 = (unsigned short*)alloc((size_t)512 * 512 * 2);
  unsigned short* zn1 = (unsigned short*)alloc((size_t)512 * 512 * 2);
  unsigned short* e10 = (unsigned short*)alloc((size_t)2048 * 512 * 2);
  unsigned short* e11 = (unsigned short*)alloc((size_t)2048 * 512 * 2);
  float*  e2f  = (float*)alloc((size_t)2048 * 512 * 4);
  float*  sc   = (float*)alloc((size_t)2048 * 512 * 4);
  int*    zi   = (int*)alloc(2048 * 4);
  unsigned short* w0 = (unsigned short*)alloc((size_t)512 * 8192 * 2);
  unsigned short* w1 = (unsigned short*)alloc((size_t)512 * 8192 * 2);
  unsigned short* w2 = (unsigned short*)alloc((size_t)512 * 8192 * 2);
  float*  act  = (float*)alloc((size_t)2048 * 8192 * 4);
  float*  P    = (float*)alloc((size_t)4 * 2048 * 512 * 4);
  const size_t slab = (size_t)2048 * 512;

  prep_table_kernel<<<1, 128, 0, stream>>>(se, tbl);
  norm_split_kernel<<<512, 256, 0, stream>>>(zv, znf, zn0, zn1, 0.0f);

  // ---- tower 1 -> act ; split p1 weights ; 3-product MFMA GEMM ; norm ----
  split_kernel<2><<<4096, 256, 0, stream>>>(p1lw, w0, w1, nullptr, 1048576);
  tower_kernel<<<2048, 256, 0, stream>>>(s, sprime, tbl, ew, eb,
                                         p1c1w, p1c1b, p1c2w, p1c2b, act, 0);
  mfma_gemm_kernel<2, true, false, false><<<dim3(16, 4, 4), 256, 0, stream>>>(
      act, nullptr, nullptr, w0, w1, nullptr, nullptr, nullptr,
      P, 2048, 512, 8192, 2048);
  reduce_norm_kernel<<<2048, 256, 0, stream>>>(P, 4, slab, p1lb, 1e-4f,
                                               nullptr, e10, e11);

  // ---- tower 2 (delta) -> act ; split p2 weights ; 6-product GEMM ; norm ----
  split_kernel<3><<<4096, 256, 0, stream>>>(p2lw, w0, w1, w2, 1048576);
  tower_kernel<<<2048, 256, 0, stream>>>(s, sprime, tbl, ew, eb,
                                         p2c1w, p2c1b, p2c2w, p2c2b, act, 1);
  mfma_gemm_kernel<3, true, false, false><<<dim3(16, 4, 4), 256, 0, stream>>>(
      act, nullptr, nullptr, w0, w1, w2, nullptr, nullptr,
      P, 2048, 512, 8192, 2048);
  reduce_norm_kernel<<<2048, 256, 0, stream>>>(P, 4, slab, p2lb, 1e-4f,
                                               e2f, nullptr, nullptr);

  // ---- scores (f32, argmax-critical) -> argmax -> final gathered GEMM ----
  gemm_bt_kernel<<<dim3(32, 8), 256, 0, stream>>>(e2f, znf, nullptr, nullptr,
                                                  nullptr, sc, 2048, 512, 512);
  argmax_rows_kernel<<<2048, 256, 0, stream>>>(sc, zi);
  mfma_gemm_kernel<2, false, true, true><<<dim3(16, 16, 1), 256, 0, stream>>>(
      nullptr, e10, e11, zn0, zn1, nullptr, zi, scale,
      out, 2048, 2048, 512, 512);
}

// Round 3
// 486.431 us; speedup vs baseline: 2.8381x; 1.8734x over previous
//
#include <hip/hip_runtime.h>
#include <math.h>

// ---------------------------------------------------------------------------
// Problem: B=2048, H=W=16, DICT=14, SE=8, CE=16, ESZ=512, NZ=512
// out = (2048,2048) f32.  All heavy math on MFMA via split-bf16:
//   tower1 / final path : 2-way split, 3 products  (~1.5e-5 rel)
//   tower2 / argmax path: 3-way split, 6 products  (~f32-equivalent)
// ---------------------------------------------------------------------------

typedef __attribute__((ext_vector_type(8))) __bf16 bf16x8;
typedef __attribute__((ext_vector_type(4))) float f32x4;
typedef __attribute__((ext_vector_type(8))) unsigned short ushort8;
typedef __attribute__((ext_vector_type(4))) unsigned short ushort4v;

static __device__ __forceinline__ unsigned short f2bf(float x) {
  union { float f; unsigned u; } v; v.f = x;
  return (unsigned short)(v.u >> 16);
}
static __device__ __forceinline__ float bf2f(unsigned short h) {
  union { float f; unsigned u; } v; v.u = ((unsigned)h) << 16;
  return v.f;
}
template<int NS>
static __device__ __forceinline__ void split3(float x, unsigned short* h) {
  unsigned short q0 = f2bf(x); h[0] = q0;
  float r1 = x - bf2f(q0);
  unsigned short q1 = f2bf(r1); h[1] = q1;
  if constexpr (NS == 3) h[2] = f2bf(r1 - bf2f(q1));
}
static __device__ __forceinline__ void gload_lds16(const void* g, void* l) {
  __builtin_amdgcn_global_load_lds(
      (const __attribute__((address_space(1))) unsigned int*)g,
      (__attribute__((address_space(3))) unsigned int*)l, 16, 0, 0);
}
#define MFMA16(a, b, c) __builtin_amdgcn_mfma_f32_16x16x32_bf16((a), (b), (c), 0, 0, 0)

template<int NS>
static __device__ __forceinline__ f32x4 mfma_prod(const bf16x8* a, const bf16x8* b, f32x4 c) {
  c = MFMA16(a[0], b[0], c);
  c = MFMA16(a[0], b[1], c);
  c = MFMA16(a[1], b[0], c);
  if constexpr (NS == 3) {
    c = MFMA16(a[1], b[1], c);
    c = MFMA16(a[0], b[2], c);
    c = MFMA16(a[2], b[0], c);
  }
  return c;
}
// swizzled ushort16-unit index for the [cell][16ch] conv act buffers
static __device__ __forceinline__ int conv_a16(int cell, int half) {
  return (cell * 2 + half) ^ ((cell >> 2) & 7);
}

// ---------------------------------------------------------------------------
// K0: table = se / max(||row||,1)   (14x8)
// ---------------------------------------------------------------------------
__global__ __launch_bounds__(128) void prep_table_kernel(
    const float* __restrict__ se, float* __restrict__ tbl)
{
  int t = threadIdx.x;
  if (t < 112) {
    int r = t >> 3;
    float ss = 0.f;
    #pragma unroll
    for (int i = 0; i < 8; ++i) { float v = se[r * 8 + i]; ss += v * v; }
    float n = fmaxf(sqrtf(ss), 1.0f);
    tbl[t] = se[t] / n;
  }
}

// ---------------------------------------------------------------------------
// K1: row-normalize (rows x 512) with optional bias, emit 2-3 bf16 splits
//     out = (in+bias) / (sqrt(sum^2)+eps)
// ---------------------------------------------------------------------------
__global__ __launch_bounds__(256) void reduce_norm_kernel(
    const float* __restrict__ pre, const float* __restrict__ bias, float eps,
    unsigned short* __restrict__ o0, unsigned short* __restrict__ o1,
    unsigned short* __restrict__ o2)
{
  int row = blockIdx.x, t = threadIdx.x;
  size_t base = (size_t)row * 512 + t * 2;
  float2 v = *reinterpret_cast<const float2*>(pre + base);
  float ax = v.x, ay = v.y;
  if (bias) { ax += bias[t * 2]; ay += bias[t * 2 + 1]; }
  float ss = ax * ax + ay * ay;
  #pragma unroll
  for (int m = 32; m >= 1; m >>= 1) ss += __shfl_xor(ss, m, 64);
  __shared__ float wsum[4];
  int lane = t & 63, wid = t >> 6;
  if (lane == 0) wsum[wid] = ss;
  __syncthreads();
  float tot = wsum[0] + wsum[1] + wsum[2] + wsum[3];
  float inv = 1.0f / (sqrtf(tot) + eps);
  float a = ax * inv, b = ay * inv;
  unsigned short ha[3], hb[3];
  split3<3>(a, ha); split3<3>(b, hb);
  o0[base] = ha[0]; o0[base + 1] = hb[0];
  o1[base] = ha[1]; o1[base + 1] = hb[1];
  if (o2) { o2[base] = ha[2]; o2[base + 1] = hb[2]; }
}

// ---------------------------------------------------------------------------
// K2: pre-split+transpose conv weights into MFMA-B-fragment layout
//   dst[sp][s][kc][oc][ic8] (ushort), NSs K-steps, OC channels
//   mode 0 (embed, IC=8): tap = s*4+kc,        icf = ic
//   mode 1 (conv, IC=16): tap = s*2+(kc>>1),   icf = (kc&1)*8+ic
//   tap >= 9 -> 0 (K padding)
// ---------------------------------------------------------------------------
__global__ __launch_bounds__(256) void prep_wt_kernel(
    const float* __restrict__ src, unsigned short* __restrict__ dst,
    int NSs, int OC, int mode)
{
  int total = 3 * NSs * 4 * OC * 8;
  int i = blockIdx.x * 256 + threadIdx.x;
  if (i >= total) return;
  int ic = i & 7;
  int r = i >> 3;
  int oc = r % OC; r /= OC;
  int kc = r & 3; r >>= 2;
  int s = r % NSs;
  int sp = r / NSs;
  int tap, icf, IC;
  if (mode == 0) { tap = s * 4 + kc; icf = ic; IC = 8; }
  else           { tap = s * 2 + (kc >> 1); icf = (kc & 1) * 8 + ic; IC = 16; }
  float w = 0.f;
  if (tap < 9) {
    int ky = tap / 3, kx = tap - ky * 3;
    w = src[((oc * IC + icf) * 3 + ky) * 3 + kx];
  }
  unsigned short h[3];
  split3<3>(w, h);
  dst[i] = h[sp];
}

// ---------------------------------------------------------------------------
// K3: fused MFMA tower. One block = one image, 256 threads = 4 waves.
//   gather+split -> G[cell][8ch]          (16x16 + zero halo -> 18x18)
//   embed conv (8->16, K=9taps*8ic packed 4taps/step, 3 steps) -> Abuf
//   conv1 (16->16, K=9taps*16ic packed 2taps/step, 5 steps), relu -> Bbuf
//   conv2 (16->32), relu -> global act splits [b][oc*256+px]
// A-frag: lane&15 = x (pixel in row), lane>>4 = k-group; M-tile = image row y.
// Conv act buffers: [cell][16ch] bf16 per split with XOR swizzle conv_a16
// applied identically on write (epilogue) and read (A-frag).
// ---------------------------------------------------------------------------
template<int NS>
__global__ __launch_bounds__(256) void tower_mfma_kernel(
    const int* __restrict__ sIdx, const int* __restrict__ spIdx,
    const float* __restrict__ tblf,
    const unsigned short* __restrict__ wtE,
    const unsigned short* __restrict__ wt1,
    const unsigned short* __restrict__ wt2,
    const float* __restrict__ eb, const float* __restrict__ c1b,
    const float* __restrict__ c2b,
    unsigned short* __restrict__ a0, unsigned short* __restrict__ a1,
    unsigned short* __restrict__ a2, int delta)
{
  __shared__ float tbl[112];
  __shared__ ushort8 G[NS][324];      // [cell][8ch]
  __shared__ ushort8 Abuf[NS][648];   // [cell][16ch] swizzled
  __shared__ ushort8 Bbuf[NS][648];

  const int b = blockIdx.x, t = threadIdx.x;
  const int lane = t & 63, wv = t >> 6;
  const int fr = lane & 15, kc = lane >> 4;

  if (t < 112) tbl[t] = tblf[t];
  {
    int4 zz = {0, 0, 0, 0};
    int4* gz = (int4*)G;
    for (int i = t; i < NS * 324; i += 256) gz[i] = zz;
    int4* az = (int4*)Abuf;
    for (int i = t; i < NS * 648; i += 256) az[i] = zz;
    int4* bz = (int4*)Bbuf;
    for (int i = t; i < NS * 648; i += 256) bz[i] = zz;
  }
  __syncthreads();

  // ---- gather + split -> G ----
  {
    const int y = t >> 4, x = t & 15;
    const int cell = (y + 1) * 18 + (x + 1);
    int sv = sIdx[(size_t)b * 256 + t];
    float v[8];
    if (delta) {
      int spv = spIdx[(size_t)b * 256 + t];
      #pragma unroll
      for (int c = 0; c < 8; ++c) v[c] = tbl[spv * 8 + c] - tbl[sv * 8 + c];
    } else {
      #pragma unroll
      for (int c = 0; c < 8; ++c) v[c] = tbl[sv * 8 + c];
    }
    ushort8 h0, h1, h2;
    #pragma unroll
    for (int c = 0; c < 8; ++c) {
      unsigned short q[3];
      split3<NS>(v[c], q);
      h0[c] = q[0]; h1[c] = q[1];
      if constexpr (NS == 3) h2[c] = q[2];
    }
    G[0][cell] = h0; G[1][cell] = h1;
    if constexpr (NS == 3) G[2][cell] = h2;
  }
  __syncthreads();

  // ---- embed conv 8->16 (no relu; bias only for tower1) -> Abuf ----
  {
    float bias = 0.f;
    if (!delta) bias = eb[fr];
    f32x4 acc[4];
    #pragma unroll
    for (int j = 0; j < 4; ++j) acc[j] = (f32x4)0.f;
    #pragma unroll
    for (int s = 0; s < 3; ++s) {
      bf16x8 bw[NS];
      #pragma unroll
      for (int sp = 0; sp < NS; ++sp)
        bw[sp] = __builtin_bit_cast(bf16x8, *reinterpret_cast<const ushort8*>(
            wtE + (size_t)(((sp * 3 + s) * 4 + kc) * 16 + fr) * 8));
      int tap = s * 4 + kc; if (tap > 8) tap = 8;
      const int dy = tap / 3, dx = tap - dy * 3;
      const int cb = dy * 18 + fr + dx;
      #pragma unroll
      for (int j = 0; j < 4; ++j) {
        const int cell = cb + (wv * 4 + j) * 18;
        bf16x8 av[NS];
        #pragma unroll
        for (int sp = 0; sp < NS; ++sp)
          av[sp] = __builtin_bit_cast(bf16x8, G[sp][cell]);
        acc[j] = mfma_prod<NS>(av, bw, acc[j]);
      }
    }
    // epilogue: C col=lane&15=oc, row=(lane>>4)*4+q = x
    #pragma unroll
    for (int j = 0; j < 4; ++j) {
      const int y = wv * 4 + j;
      #pragma unroll
      for (int q = 0; q < 4; ++q) {
        const int x = kc * 4 + q;
        const int cell = (y + 1) * 18 + (x + 1);
        const int a16 = conv_a16(cell, fr >> 3);
        unsigned short hh[3];
        split3<NS>(acc[j][q] + bias, hh);
        #pragma unroll
        for (int sp = 0; sp < NS; ++sp)
          ((unsigned short*)&Abuf[sp][0])[a16 * 8 + (fr & 7)] = hh[sp];
      }
    }
  }
  __syncthreads();

  // ---- conv1 16->16, relu -> Bbuf ----
  {
    const float bias = c1b[fr];
    f32x4 acc[4];
    #pragma unroll
    for (int j = 0; j < 4; ++j) acc[j] = (f32x4)0.f;
    #pragma unroll
    for (int s = 0; s < 5; ++s) {
      bf16x8 bw[NS];
      #pragma unroll
      for (int sp = 0; sp < NS; ++sp)
        bw[sp] = __builtin_bit_cast(bf16x8, *reinterpret_cast<const ushort8*>(
            wt1 + (size_t)(((sp * 5 + s) * 4 + kc) * 16 + fr) * 8));
      int tap = s * 2 + (kc >> 1); if (tap > 8) tap = 8;
      const int dy = tap / 3, dx = tap - dy * 3;
      const int half = kc & 1;
      const int cb = dy * 18 + fr + dx;
      #pragma unroll
      for (int j = 0; j < 4; ++j) {
        const int cell = cb + (wv * 4 + j) * 18;
        const int a16 = conv_a16(cell, half);
        bf16x8 av[NS];
        #pragma unroll
        for (int sp = 0; sp < NS; ++sp)
          av[sp] = __builtin_bit_cast(bf16x8, *reinterpret_cast<const ushort8*>(
              (const unsigned short*)&Abuf[sp][0] + a16 * 8));
        acc[j] = mfma_prod<NS>(av, bw, acc[j]);
      }
    }
    #pragma unroll
    for (int j = 0; j < 4; ++j) {
      const int y = wv * 4 + j;
      #pragma unroll
      for (int q = 0; q < 4; ++q) {
        const int x = kc * 4 + q;
        const int cell = (y + 1) * 18 + (x + 1);
        const int a16 = conv_a16(cell, fr >> 3);
        unsigned short hh[3];
        split3<NS>(fmaxf(acc[j][q] + bias, 0.f), hh);
        #pragma unroll
        for (int sp = 0; sp < NS; ++sp)
          ((unsigned short*)&Bbuf[sp][0])[a16 * 8 + (fr & 7)] = hh[sp];
      }
    }
  }
  __syncthreads();

  // ---- conv2 16->32, relu -> global act splits ----
  {
    const float bias0 = c2b[fr], bias1 = c2b[16 + fr];
    f32x4 acc0[4], acc1[4];
    #pragma unroll
    for (int j = 0; j < 4; ++j) { acc0[j] = (f32x4)0.f; acc1[j] = (f32x4)0.f; }
    #pragma unroll
    for (int s = 0; s < 5; ++s) {
      bf16x8 bw0[NS], bw1[NS];
      #pragma unroll
      for (int sp = 0; sp < NS; ++sp) {
        size_t base = (size_t)(((sp * 5 + s) * 4 + kc) * 32) * 8;
        bw0[sp] = __builtin_bit_cast(bf16x8,
            *reinterpret_cast<const ushort8*>(wt2 + base + (size_t)fr * 8));
        bw1[sp] = __builtin_bit_cast(bf16x8,
            *reinterpret_cast<const ushort8*>(wt2 + base + (size_t)(16 + fr) * 8));
      }
      int tap = s * 2 + (kc >> 1); if (tap > 8) tap = 8;
      const int dy = tap / 3, dx = tap - dy * 3;
      const int half = kc & 1;
      const int cb = dy * 18 + fr + dx;
      #pragma unroll
      for (int j = 0; j < 4; ++j) {
        const int cell = cb + (wv * 4 + j) * 18;
        const int a16 = conv_a16(cell, half);
        bf16x8 av[NS];
        #pragma unroll
        for (int sp = 0; sp < NS; ++sp)
          av[sp] = __builtin_bit_cast(bf16x8, *reinterpret_cast<const ushort8*>(
              (const unsigned short*)&Bbuf[sp][0] + a16 * 8));
        acc0[j] = mfma_prod<NS>(av, bw0, acc0[j]);
        acc1[j] = mfma_prod<NS>(av, bw1, acc1[j]);
      }
    }
    #pragma unroll
    for (int j = 0; j < 4; ++j) {
      const int y = wv * 4 + j;
      ushort4v g0[2], g1[2], g2[2];
      #pragma unroll
      for (int q = 0; q < 4; ++q) {
        unsigned short hh[3];
        split3<NS>(fmaxf(acc0[j][q] + bias0, 0.f), hh);
        g0[0][q] = hh[0]; g1[0][q] = hh[1]; if constexpr (NS == 3) g2[0][q] = hh[2];
        split3<NS>(fmaxf(acc1[j][q] + bias1, 0.f), hh);
        g0[1][q] = hh[0]; g1[1][q] = hh[1]; if constexpr (NS == 3) g2[1][q] = hh[2];
      }
      size_t base0 = (size_t)b * 8192 + (size_t)fr * 256 + y * 16 + kc * 4;
      size_t base1 = base0 + 16 * 256;
      *reinterpret_cast<ushort4v*>(a0 + base0) = g0[0];
      *reinterpret_cast<ushort4v*>(a0 + base1) = g0[1];
      *reinterpret_cast<ushort4v*>(a1 + base0) = g1[0];
      *reinterpret_cast<ushort4v*>(a1 + base1) = g1[1];
      if constexpr (NS == 3) {
        *reinterpret_cast<ushort4v*>(a2 + base0) = g2[0];
        *reinterpret_cast<ushort4v*>(a2 + base1) = g2[1];
      }
    }
  }
}

// ---------------------------------------------------------------------------
// K4: split-bf16 MFMA GEMM, C = A @ B^T (A: MxK row-major splits, B: NxK)
//   128x128 tile, BK=32, 4 waves, 4x4 16x16 frags per wave.
//   A: pre-split, NS tiles via global_load_lds (pre-swizzled source col).
//   B: BF32 ? split f32 rows on the fly : pre-split gload (+optional gather).
//   Epilogue: ATOMIC ? atomicAdd f32 (K-split reduction) :
//             write (FINAL: * exp(scale)).
// ---------------------------------------------------------------------------
template<int NS, bool BF32, bool GATHER, bool ATOMIC, bool FINAL>
__global__ __launch_bounds__(256) void mfma_gemm_kernel(
    const unsigned short* __restrict__ A0, const unsigned short* __restrict__ A1,
    const unsigned short* __restrict__ A2,
    const unsigned short* __restrict__ B0, const unsigned short* __restrict__ B1,
    const unsigned short* __restrict__ B2,
    const float* __restrict__ Bf32,
    const int* __restrict__ gather, const float* __restrict__ scale_p,
    float* __restrict__ C, int M, int N, int K, int Ksub)
{
  __shared__ unsigned short ldsA[NS][4096];
  __shared__ unsigned short ldsB[NS][4096];

  const int t = threadIdx.x;
  const int lane = t & 63, wv = t >> 6;
  const int m0 = blockIdx.x * 128, n0 = blockIdx.y * 128;
  const long kbase = (long)blockIdx.z * Ksub;
  const int NT = Ksub >> 5;

  const int st_row = lane >> 2;
  const int st_cb = (lane & 3) * 16;
  int srow[2];
  long bgrow[2];
  #pragma unroll
  for (int r = 0; r < 2; ++r) {
    srow[r] = (wv + 4 * r) * 16 + st_row;
    if constexpr (!BF32) {
      long g = n0 + srow[r];
      if constexpr (GATHER) g = gather[n0 + srow[r]];
      bgrow[r] = g;
    }
  }

  const int wr = wv >> 1, wc = wv & 1;
  const int fr = lane & 15, kc = lane >> 4;

  f32x4 acc[4][4];
  #pragma unroll
  for (int mi = 0; mi < 4; ++mi)
    #pragma unroll
    for (int ni = 0; ni < 4; ++ni) acc[mi][ni] = (f32x4)0.f;

  const unsigned short* Asp[3] = {A0, A1, A2};
  const unsigned short* Bsp[3] = {B0, B1, B2};

  for (int kt = 0; kt < NT; ++kt) {
    const long k0 = kbase + (long)kt * 32;
    // A staging (pre-split, async)
    #pragma unroll
    for (int sp = 0; sp < NS; ++sp)
      #pragma unroll
      for (int r = 0; r < 2; ++r) {
        int row = srow[r];
        int c = st_cb ^ (((row >> 1) & 3) << 4);
        gload_lds16(Asp[sp] + (size_t)(m0 + row) * K + k0 + (c >> 1),
                    &ldsA[sp][(wv + 4 * r) * 512]);
      }
    // B staging
    if constexpr (BF32) {
      #pragma unroll
      for (int i = 0; i < 4; ++i) {
        int row = (t >> 3) + 32 * i;
        f32x4 v = *reinterpret_cast<const f32x4*>(
            Bf32 + (size_t)(n0 + row) * K + k0 + (t & 7) * 4);
        int cb = ((t & 7) * 8) ^ (((row >> 1) & 3) << 4);
        ushort4v w0, w1, w2;
        #pragma unroll
        for (int jj = 0; jj < 4; ++jj) {
          unsigned short hh[3];
          split3<NS>(v[jj], hh);
          w0[jj] = hh[0]; w1[jj] = hh[1];
          if constexpr (NS == 3) w2[jj] = hh[2];
        }
        *reinterpret_cast<ushort4v*>(&ldsB[0][row * 32 + (cb >> 1)]) = w0;
        *reinterpret_cast<ushort4v*>(&ldsB[1][row * 32 + (cb >> 1)]) = w1;
        if constexpr (NS == 3)
          *reinterpret_cast<ushort4v*>(&ldsB[2][row * 32 + (cb >> 1)]) = w2;
      }
    } else {
      #pragma unroll
      for (int sp = 0; sp < NS; ++sp)
        #pragma unroll
        for (int r = 0; r < 2; ++r) {
          int row = srow[r];
          int c = st_cb ^ (((row >> 1) & 3) << 4);
          gload_lds16(Bsp[sp] + (size_t)bgrow[r] * K + k0 + (c >> 1),
                      &ldsB[sp][(wv + 4 * r) * 512]);
        }
    }
    __syncthreads();

    bf16x8 af[NS][4], bf[NS][4];
    #pragma unroll
    for (int sp = 0; sp < NS; ++sp) {
      #pragma unroll
      for (int mi = 0; mi < 4; ++mi) {
        int row = wr * 64 + mi * 16 + fr;
        int cb = (kc * 16) ^ (((row >> 1) & 3) << 4);
        af[sp][mi] = __builtin_bit_cast(bf16x8,
            *reinterpret_cast<const ushort8*>(&ldsA[sp][row * 32 + (cb >> 1)]));
      }
      #pragma unroll
      for (int ni = 0; ni < 4; ++ni) {
        int row = wc * 64 + ni * 16 + fr;
        int cb = (kc * 16) ^ (((row >> 1) & 3) << 4);
        bf[sp][ni] = __builtin_bit_cast(bf16x8,
            *reinterpret_cast<const ushort8*>(&ldsB[sp][row * 32 + (cb >> 1)]));
      }
    }
    #pragma unroll
    for (int mi = 0; mi < 4; ++mi)
      #pragma unroll
      for (int ni = 0; ni < 4; ++ni) {
        f32x4 c = acc[mi][ni];
        c = MFMA16(af[0][mi], bf[0][ni], c);
        c = MFMA16(af[0][mi], bf[1][ni], c);
        c = MFMA16(af[1][mi], bf[0][ni], c);
        if constexpr (NS == 3) {
          c = MFMA16(af[1][mi], bf[1][ni], c);
          c = MFMA16(af[0][mi], bf[2][ni], c);
          c = MFMA16(af[2][mi], bf[0][ni], c);
        }
        acc[mi][ni] = c;
      }
    __syncthreads();
  }

  // epilogue: C/D layout col=lane&15, row=(lane>>4)*4+q
  if constexpr (ATOMIC) {
    #pragma unroll
    for (int mi = 0; mi < 4; ++mi)
      #pragma unroll
      for (int ni = 0; ni < 4; ++ni) {
        int col = n0 + wc * 64 + ni * 16 + fr;
        #pragma unroll
        for (int q = 0; q < 4; ++q) {
          int row = m0 + wr * 64 + mi * 16 + kc * 4 + q;
          atomicAdd(&C[(size_t)row * N + col], acc[mi][ni][q]);
        }
      }
  } else {
    float scl = 1.0f;
    if constexpr (FINAL) scl = expf(scale_p[0]);
    #pragma unroll
    for (int mi = 0; mi < 4; ++mi)
      #pragma unroll
      for (int ni = 0; ni < 4; ++ni) {
        int col = n0 + wc * 64 + ni * 16 + fr;
        #pragma unroll
        for (int q = 0; q < 4; ++q) {
          int row = m0 + wr * 64 + mi * 16 + kc * 4 + q;
          C[(size_t)row * N + col] = acc[mi][ni][q] * scl;
        }
      }
  }
}

// ---------------------------------------------------------------------------
// K5: per-row argmax over 512 scores (first-occurrence tie-break)
// ---------------------------------------------------------------------------
__global__ __launch_bounds__(256) void argmax_rows_kernel(
    const float* __restrict__ S, int* __restrict__ inds)
{
  __shared__ float vals[256];
  __shared__ int idxs[256];
  int row = blockIdx.x, t = threadIdx.x;
  float best = -INFINITY; int bi = 1 << 30;
  #pragma unroll
  for (int r = 0; r < 2; ++r) {
    int j = t + r * 256;
    float v = S[(size_t)row * 512 + j];
    if (v > best) { best = v; bi = j; }
  }
  vals[t] = best; idxs[t] = bi;
  __syncthreads();
  for (int off = 128; off > 0; off >>= 1) {
    if (t < off) {
      float v2 = vals[t + off]; int i2 = idxs[t + off];
      if (v2 > vals[t] || (v2 == vals[t] && i2 < idxs[t])) {
        vals[t] = v2; idxs[t] = i2;
      }
    }
    __syncthreads();
  }
  if (t == 0) inds[row] = idxs[0];
}

// ---------------------------------------------------------------------------
// launch
// ---------------------------------------------------------------------------
extern "C" void kernel_launch(void* const* d_in, const int* in_sizes, int n_in,
                              void* d_out, int out_size, void* d_ws, size_t ws_size,
                              hipStream_t stream)
{
  const int*   s      = (const int*)  d_in[0];
  const int*   sprime = (const int*)  d_in[1];
  const float* se     = (const float*)d_in[2];
  const float* ew     = (const float*)d_in[3];
  const float* eb     = (const float*)d_in[4];
  const float* p1c1w  = (const float*)d_in[5];
  const float* p1c1b  = (const float*)d_in[6];
  const float* p1c2w  = (const float*)d_in[7];
  const float* p1c2b  = (const float*)d_in[8];
  const float* p1lw   = (const float*)d_in[9];
  const float* p1lb   = (const float*)d_in[10];
  const float* p2c1w  = (const float*)d_in[11];
  const float* p2c1b  = (const float*)d_in[12];
  const float* p2c2w  = (const float*)d_in[13];
  const float* p2c2b  = (const float*)d_in[14];
  const float* p2lw   = (const float*)d_in[15];
  const float* p2lb   = (const float*)d_in[16];
  const float* zv     = (const float*)d_in[17];
  const float* scale  = (const float*)d_in[18];
  float* out = (float*)d_out;

  // ---- workspace (peak ~112 MB, <= proven 118 MB) ----
  char* w = (char*)d_ws;
  size_t off = 0;
  auto alloc = [&](size_t bytes) -> char* {
    char* p = w + off;
    off += (bytes + 255) & ~(size_t)255;
    return p;
  };
  float* tblf = (float*)alloc(112 * 4);
  unsigned short* zn0 = (unsigned short*)alloc((size_t)512 * 512 * 2);
  unsigned short* zn1 = (unsigned short*)alloc((size_t)512 * 512 * 2);
  unsigned short* zn2 = (unsigned short*)alloc((size_t)512 * 512 * 2);
  unsigned short* e10 = (unsigned short*)alloc((size_t)2048 * 512 * 2);
  unsigned short* e11 = (unsigned short*)alloc((size_t)2048 * 512 * 2);
  unsigned short* e20 = (unsigned short*)alloc((size_t)2048 * 512 * 2);
  unsigned short* e21 = (unsigned short*)alloc((size_t)2048 * 512 * 2);
  unsigned short* e22 = (unsigned short*)alloc((size_t)2048 * 512 * 2);
  float* epre = (float*)alloc((size_t)2048 * 512 * 4);
  float* sc   = epre;                       // alias: epre dead before score GEMM
  int*   zi   = (int*)alloc(2048 * 4);
  unsigned short* wtE  = (unsigned short*)alloc(4608 * 2);
  unsigned short* wt1a = (unsigned short*)alloc(7680 * 2);
  unsigned short* wt2a = (unsigned short*)alloc(15360 * 2);
  unsigned short* wt1b = (unsigned short*)alloc(7680 * 2);
  unsigned short* wt2b = (unsigned short*)alloc(15360 * 2);
  unsigned short* act0 = (unsigned short*)alloc((size_t)2048 * 8192 * 2);
  unsigned short* act1 = (unsigned short*)alloc((size_t)2048 * 8192 * 2);
  unsigned short* act2 = (unsigned short*)alloc((size_t)2048 * 8192 * 2);

  prep_table_kernel<<<1, 128, 0, stream>>>(se, tblf);
  reduce_norm_kernel<<<512, 256, 0, stream>>>(zv, nullptr, 0.0f, zn0, zn1, zn2);
  prep_wt_kernel<<<18, 256, 0, stream>>>(ew,    wtE,  3, 16, 0);
  prep_wt_kernel<<<30, 256, 0, stream>>>(p1c1w, wt1a, 5, 16, 1);
  prep_wt_kernel<<<60, 256, 0, stream>>>(p1c2w, wt2a, 5, 32, 1);
  prep_wt_kernel<<<30, 256, 0, stream>>>(p2c1w, wt1b, 5, 16, 1);
  prep_wt_kernel<<<60, 256, 0, stream>>>(p2c2w, wt2b, 5, 32, 1);

  // ---- tower 1 (2-way split) -> act0/1 ; linear ; norm -> e1 splits ----
  tower_mfma_kernel<2><<<2048, 256, 0, stream>>>(
      s, sprime, tblf, wtE, wt1a, wt2a, eb, p1c1b, p1c2b, act0, act1, act2, 0);
  hipMemsetAsync(epre, 0, (size_t)2048 * 512 * 4, stream);
  mfma_gemm_kernel<2, true, false, true, false><<<dim3(16, 4, 8), 256, 0, stream>>>(
      act0, act1, nullptr, nullptr, nullptr, nullptr, p1lw, nullptr, nullptr,
      epre, 2048, 512, 8192, 1024);
  reduce_norm_kernel<<<2048, 256, 0, stream>>>(epre, p1lb, 1e-4f, e10, e11, nullptr);

  // ---- tower 2 (3-way split, argmax-critical) -> act0/1/2 ; linear ; norm --
  tower_mfma_kernel<3><<<2048, 256, 0, stream>>>(
      s, sprime, tblf, wtE, wt1b, wt2b, eb, p2c1b, p2c2b, act0, act1, act2, 1);
  hipMemsetAsync(epre, 0, (size_t)2048 * 512 * 4, stream);
  mfma_gemm_kernel<3, true, false, true, false><<<dim3(16, 4, 8), 256, 0, stream>>>(
      act0, act1, act2, nullptr, nullptr, nullptr, p2lw, nullptr, nullptr,
      epre, 2048, 512, 8192, 1024);
  reduce_norm_kernel<<<2048, 256, 0, stream>>>(epre, p2lb, 1e-4f, e20, e21, e22);

  // ---- scores (6-product MFMA) -> argmax -> final gathered GEMM ----
  mfma_gemm_kernel<3, false, false, false, false><<<dim3(16, 4, 1), 256, 0, stream>>>(
      e20, e21, e22, zn0, zn1, zn2, nullptr, nullptr, nullptr,
      sc, 2048, 512, 512, 512);
  argmax_rows_kernel<<<2048, 256, 0, stream>>>(sc, zi);
  mfma_gemm_kernel<2, false, true, false, true><<<dim3(16, 16, 1), 256, 0, stream>>>(
      e10, e11, nullptr, zn0, zn1, nullptr, nullptr, zi, scale,
      out, 2048, 2048, 512, 512);
}